// Round 16
// baseline (47.574 us; speedup 1.0000x reference)
//
#include <hip/hip_runtime.h>

#define NEGINF -1000000000.0f
#define L2E 1.44269504088896340736f

typedef __attribute__((ext_vector_type(4))) float f32x4;
typedef _Float16 half8 __attribute__((ext_vector_type(8)));
typedef _Float16 half4 __attribute__((ext_vector_type(4)));

__device__ inline float exp2fast(float x) { return __builtin_amdgcn_exp2f(x); }

constexpr int Bn = 64, Cn = 1024, Qn = 128, Dn = 128;
constexpr int QSTR = 136;   // halves; 272 B rows -> 2-way (free) b128 bank pattern

// LDS map (bytes), total 72768 -> 2 blocks/CU:
//   0      qrow [128][136] fp16 = 34816  } overlaid by partf [16][128] f32 = 8192 (after mm1)
//   34816  qT2  [128][136] fp16 = 34816
//   69632  wfull 384 f (1536)  — all * log2(e)
//   71168  qts  128 f          — log2-scaled
//   71680  mloc 128 f
//   72192  wv   128 f
//   72704  red  16 f (64)

__global__ __launch_bounds__(512, 4) void k1_kernel(
    const float* __restrict__ ctx, const float* __restrict__ qry,
    const float* __restrict__ W, const float* __restrict__ mask,
    float* __restrict__ out, float* __restrict__ ws_part, float* __restrict__ ws_ms)
{
    __shared__ char smem[72768];
    _Float16* qrow = (_Float16*)smem;
    _Float16* qT2  = (_Float16*)(smem + 34816);
    float* wfull = (float*)(smem + 69632);
    float* qts   = (float*)(smem + 71168);
    float* mloc  = (float*)(smem + 71680);
    float* wv    = (float*)(smem + 72192);
    float* red   = (float*)(smem + 72704);
    float* partf = (float*)smem;   // overlays qrow (dead after mm1 / post-mm2 barrier)

    // XCD grouping: grid (Bn, 8); flat wgid = b + 64*cg -> xcd = b%8 for all 8
    // tiles of batch b => the batch's query slab is fetched into ONE XCD L2.
    const int b = blockIdx.x, cg = blockIdx.y, c0 = cg * 128;
    const int t = threadIdx.x;
    const float* ctxB = ctx + (size_t)b * Cn * Dn;
    const float* qryB = qry + (size_t)b * Qn * Dn;

    if (t < 384) wfull[t] = W[t] * L2E;
    __syncthreads();

    // ---- phase 1: stage query fp16 (row-major + bijection-transposed); qterm(+mask)
    {
        int q = t >> 2, h = t & 3;
        const float* qr = qryB + q * Dn + h * 32;
        int p = ((q >> 5) << 5) + 8 * ((q >> 2) & 3) + (q & 3) + 4 * ((q >> 4) & 1);
        float acc = 0.f;
        for (int j = 0; j < 32; j += 4) {
            f32x4 v = *(const f32x4*)(qr + j);
            int d = h * 32 + j;
            acc += v.x * wfull[128 + d] + v.y * wfull[128 + d + 1]
                 + v.z * wfull[128 + d + 2] + v.w * wfull[128 + d + 3];
            half4 hv;
            hv[0] = (_Float16)v.x; hv[1] = (_Float16)v.y;
            hv[2] = (_Float16)v.z; hv[3] = (_Float16)v.w;
            *(half4*)&qrow[q * QSTR + d] = hv;
            qT2[(d + 0) * QSTR + p] = hv[0];
            qT2[(d + 1) * QSTR + p] = hv[1];
            qT2[(d + 2) * QSTR + p] = hv[2];
            qT2[(d + 3) * QSTR + p] = hv[3];
        }
        acc += __shfl_xor(acc, 1);
        acc += __shfl_xor(acc, 2);
        if (h == 0) qts[q] = acc + (1.0f - mask[b * Qn + q]) * (NEGINF * L2E);
    }
    __syncthreads();

    const int wave = t >> 6, lane = t & 63, g = lane >> 4, l15 = lane & 15;
    const int cw = wave * 16;
    const int cl = cw + l15;   // this lane's ctx row within the 128-tile

    // ---- phase 2: mm1  S'^T[q][c] (log2-scaled fp16) with fused c_term
    f32x4 acc1[8] = {};
    float cterm = 0.f;
#pragma unroll
    for (int kk = 0; kk < 4; ++kk) {
        const int dbase = kk * 32 + g * 8;
        const float* pc = ctxB + (size_t)(c0 + cl) * Dn + dbase;
        f32x4 v0 = *(const f32x4*)pc, v1 = *(const f32x4*)(pc + 4);
        f32x4 s0 = *(const f32x4*)&wfull[256 + dbase], s1 = *(const f32x4*)&wfull[256 + dbase + 4];
        f32x4 c0w = *(const f32x4*)&wfull[dbase], c1w = *(const f32x4*)&wfull[dbase + 4];
        cterm += v0.x * c0w.x + v0.y * c0w.y + v0.z * c0w.z + v0.w * c0w.w
               + v1.x * c1w.x + v1.y * c1w.y + v1.z * c1w.z + v1.w * c1w.w;
        half8 ah;
        ah[0] = (_Float16)(v0.x * s0.x); ah[1] = (_Float16)(v0.y * s0.y);
        ah[2] = (_Float16)(v0.z * s0.z); ah[3] = (_Float16)(v0.w * s0.w);
        ah[4] = (_Float16)(v1.x * s1.x); ah[5] = (_Float16)(v1.y * s1.y);
        ah[6] = (_Float16)(v1.z * s1.z); ah[7] = (_Float16)(v1.w * s1.w);
#pragma unroll
        for (int mt = 0; mt < 8; ++mt) {
            half8 qf = *(const half8*)&qrow[(mt * 16 + l15) * QSTR + dbase];
            acc1[mt] = __builtin_amdgcn_mfma_f32_16x16x32_f16(qf, ah, acc1[mt], 0, 0, 0);
        }
    }
    cterm += __shfl_xor(cterm, 16);
    cterm += __shfl_xor(cterm, 32);   // all lanes: c_term for row cl (log2-scaled)

    // ---- phase 3: +q_term(+mask); softmax (base-2) over q per column
#pragma unroll
    for (int mt = 0; mt < 8; ++mt)
#pragma unroll
        for (int r = 0; r < 4; ++r) acc1[mt][r] += qts[mt * 16 + g * 4 + r];

    float mx = -3.4e38f;
#pragma unroll
    for (int mt = 0; mt < 8; ++mt)
#pragma unroll
        for (int r = 0; r < 4; ++r) mx = fmaxf(mx, acc1[mt][r]);
    mx = fmaxf(mx, __shfl_xor(mx, 16));
    mx = fmaxf(mx, __shfl_xor(mx, 32));
    float sum = 0.f;
#pragma unroll
    for (int mt = 0; mt < 8; ++mt)
#pragma unroll
        for (int r = 0; r < 4; ++r) {
            float pv = exp2fast(acc1[mt][r] - mx);
            acc1[mt][r] = pv;
            sum += pv;
        }
    sum += __shfl_xor(sum, 16);
    sum += __shfl_xor(sum, 32);   // full column sum for c = cw + l15 (all lanes)
    if (g == 0) mloc[cl] = mx + cterm;

    // pack P^T into B-frags (bijection k = 4g+(j&3)+16(j>>2), n = c = cw+l15)
    half8 pa[4];
#pragma unroll
    for (int kk2 = 0; kk2 < 4; ++kk2)
#pragma unroll
        for (int j = 0; j < 8; ++j)
            pa[kk2][j] = (_Float16)acc1[2 * kk2 + (j >> 2)][j & 3];

    const float is = 1.0f / sum;   // this lane's column (c = cw + l15) inverse sum

    // ---- mm2 (transposed): c2q^T[d][c] — A = qT2 (M=d), B = pa (N=c)
    // D: row d = mt*16 + 4g + r, col c = cw + l15 -> 4 consecutive d per thread.
    f32x4 acc2[8] = {};
#pragma unroll
    for (int kk2 = 0; kk2 < 4; ++kk2)
#pragma unroll
        for (int mt = 0; mt < 8; ++mt) {
            half8 qb = *(const half8*)&qT2[(mt * 16 + l15) * QSTR + kk2 * 32 + 8 * g];
            acc2[mt] = __builtin_amdgcn_mfma_f32_16x16x32_f16(qb, pa[kk2], acc2[mt], 0, 0, 0);
        }
    __syncthreads();   // qrow/qT2 reads done; mloc complete

    // ---- phase 4a: Mloc, wv, Sloc from mloc
    float vm = mloc[t & 127];
    float m = vm;
#pragma unroll
    for (int off = 1; off < 64; off <<= 1) m = fmaxf(m, __shfl_xor(m, off));
    if (lane == 0) red[wave] = m;
    __syncthreads();
    float Mloc = red[0];
#pragma unroll
    for (int i = 1; i < 8; ++i) Mloc = fmaxf(Mloc, red[i]);
    float e = exp2fast(vm - Mloc);
    if (t < 128) wv[t] = e;
    float s = e;
#pragma unroll
    for (int off = 1; off < 64; off <<= 1) s += __shfl_xor(s, off);
    if (lane == 0) red[8 + wave] = s;
    __syncthreads();
    float Sloc = red[8] + red[9];   // waves 0,1 cover t=0..127

    // ---- phase 5: direct stores of cols 1 (c2q), 2 (ctx*c2q) from acc2 frags
    {
        const int crow = c0 + cw + l15;
        const float* cbase = ctxB + (size_t)crow * Dn;
        float* orow = out + ((size_t)(b * Cn + crow)) * 512;
#pragma unroll
        for (int mt = 0; mt < 8; ++mt) {
            const int d4m = mt * 16 + 4 * g;
            f32x4 val;
            val.x = acc2[mt][0] * is; val.y = acc2[mt][1] * is;
            val.z = acc2[mt][2] * is; val.w = acc2[mt][3] * is;
            f32x4 cv = *(const f32x4*)(cbase + d4m);
            *(f32x4*)(orow + 128 + d4m) = val;
            f32x4 pr;
            pr.x = cv.x * val.x; pr.y = cv.y * val.y;
            pr.z = cv.z * val.z; pr.w = cv.w * val.w;
            *(f32x4*)(orow + 256 + d4m) = pr;
        }
    }

    // ---- phase 6: col 0 (ctx copy, coalesced) + fused q2c partial (ctx L1-hot)
    const int grp = t >> 5, d4 = (t & 31) * 4;
    f32x4 a = {};
#pragma unroll
    for (int step = 0; step < 8; ++step) {
        int c = grp + step * 16;
        f32x4 cv = *(const f32x4*)(ctxB + (size_t)(c0 + c) * Dn + d4);
        float w = wv[c];
        a.x += w * cv.x; a.y += w * cv.y; a.z += w * cv.z; a.w += w * cv.w;
        *(f32x4*)(out + ((size_t)(b * Cn + c0 + c)) * 512 + d4) = cv;
    }

    // ---- tiny tail: reduce 16 partials -> ws (partf overlays dead qrow)
    *(f32x4*)&partf[grp * 128 + d4] = a;
    __syncthreads();
    if (t < 128) {
        float s2 = 0.f;
#pragma unroll
        for (int g2 = 0; g2 < 16; ++g2) s2 += partf[g2 * 128 + t];
        ws_part[((size_t)(b * 8 + cg)) * 128 + t] = s2;
    }
    if (t == 0) {
        ws_ms[(b * 8 + cg) * 2 + 0] = Mloc;
        ws_ms[(b * 8 + cg) * 2 + 1] = Sloc;
    }
}

// ---- k3: combine chunk-partials -> q2c; write col 3 (ctx*q2c) only
__global__ __launch_bounds__(256) void k3_kernel(
    const float* __restrict__ ctx, const float* __restrict__ ws_part,
    const float* __restrict__ ws_ms, float* __restrict__ out)
{
    __shared__ float q2cs[128];
    const int ct = blockIdx.x, b = blockIdx.y, t = threadIdx.x;
    if (t < 128) {
        const float* ms = ws_ms + b * 16;
        float Mg = -3.4e38f;
#pragma unroll
        for (int i = 0; i < 8; ++i) Mg = fmaxf(Mg, ms[2 * i]);
        float num = 0.f, den = 0.f;
#pragma unroll
        for (int i = 0; i < 8; ++i) {
            float e = exp2fast(ms[2 * i] - Mg);
            num += e * ws_part[((size_t)(b * 8 + i)) * 128 + t];
            den += e * ms[2 * i + 1];
        }
        q2cs[t] = num / den;
    }
    __syncthreads();
    const float* cb = ctx + ((size_t)b * Cn + ct * 128) * Dn;
    float* ob = out + ((size_t)(b * Cn) + ct * 128) * 512;
    for (int step = 0; step < 16; ++step) {
        int c = (t >> 5) + step * 8, d4 = (t & 31) * 4;
        f32x4 v = *(const f32x4*)(cb + (size_t)c * Dn + d4);
        f32x4 q = *(const f32x4*)&q2cs[d4];
        f32x4 w;
        w.x = v.x * q.x; w.y = v.y * q.y; w.z = v.z * q.z; w.w = v.w * q.w;
        *(f32x4*)(ob + (size_t)c * 512 + 384 + d4) = w;
    }
}

extern "C" void kernel_launch(void* const* d_in, const int* in_sizes, int n_in,
                              void* d_out, int out_size, void* d_ws, size_t ws_size,
                              hipStream_t stream) {
    const float* ctx  = (const float*)d_in[0];
    const float* qry  = (const float*)d_in[1];
    const float* W    = (const float*)d_in[2];
    const float* mask = (const float*)d_in[3];
    float* out = (float*)d_out;

    float* ws_part = (float*)d_ws;                    // 64*8*128 f32
    float* ws_ms   = ws_part + (size_t)Bn * 8 * 128;  // 64*8*2 f32

    k1_kernel<<<dim3(Bn, 8), 512, 0, stream>>>(ctx, qry, W, mask, out, ws_part, ws_ms);
    k3_kernel<<<dim3(8, Bn), 256, 0, stream>>>(ctx, ws_part, ws_ms, out);
}

// Round 17
// 44.922 us; speedup vs baseline: 1.0590x; 1.0590x over previous
//
#include <hip/hip_runtime.h>

#define NEGINF -1000000000.0f
#define L2E 1.44269504088896340736f

typedef __attribute__((ext_vector_type(4))) float f32x4;
typedef _Float16 half8 __attribute__((ext_vector_type(8)));
typedef _Float16 half4 __attribute__((ext_vector_type(4)));

__device__ inline float exp2fast(float x) { return __builtin_amdgcn_exp2f(x); }

constexpr int Bn = 64, Cn = 1024, Qn = 128, Dn = 128;
constexpr int QSTR = 136;   // halves; 272 B rows -> 2-way (free) b128 bank pattern
constexpr int CSTR = 132;   // floats; 528 B rows for cq bounce

// LDS map (bytes), total 72768 -> 2 blocks/CU:
//   0      qrow [128][136] fp16 = 34816  } overlaid (after 4a) by cq [128][132] f32 = 67584
//   34816  qT2  [128][136] fp16 = 34816  }   ... then partf [16][128] f32 = 8192 (after stores)
//   69632  wfull 384 f (1536)  — all * log2(e)
//   71168  qts  128 f          — log2-scaled
//   71680  mloc 128 f
//   72192  wv   128 f
//   72704  red  16 f (64)

__global__ __launch_bounds__(512, 4) void k1_kernel(
    const float* __restrict__ ctx, const float* __restrict__ qry,
    const float* __restrict__ W, const float* __restrict__ mask,
    float* __restrict__ out, float* __restrict__ ws_part, float* __restrict__ ws_ms)
{
    __shared__ char smem[72768];
    _Float16* qrow = (_Float16*)smem;
    _Float16* qT2  = (_Float16*)(smem + 34816);
    float* wfull = (float*)(smem + 69632);
    float* qts   = (float*)(smem + 71168);
    float* mloc  = (float*)(smem + 71680);
    float* wv    = (float*)(smem + 72192);
    float* red   = (float*)(smem + 72704);
    float* cq    = (float*)smem;            // after phase 4a
    float* partf = (float*)(smem + 34816);  // after fused store loop

    // XCD grouping: grid (Bn, 8); flat wgid = b + 64*cg -> xcd = b%8 for all 8
    // tiles of batch b => the batch's query slab is fetched into ONE XCD L2.
    const int b = blockIdx.x, cg = blockIdx.y, c0 = cg * 128;
    const int t = threadIdx.x;
    const float* ctxB = ctx + (size_t)b * Cn * Dn;
    const float* qryB = qry + (size_t)b * Qn * Dn;

    if (t < 384) wfull[t] = W[t] * L2E;
    __syncthreads();

    // ---- phase 1: stage query fp16 (row-major + bijection-transposed); qterm(+mask)
    {
        int q = t >> 2, h = t & 3;
        const float* qr = qryB + q * Dn + h * 32;
        int p = ((q >> 5) << 5) + 8 * ((q >> 2) & 3) + (q & 3) + 4 * ((q >> 4) & 1);
        float acc = 0.f;
        for (int j = 0; j < 32; j += 4) {
            f32x4 v = *(const f32x4*)(qr + j);
            int d = h * 32 + j;
            acc += v.x * wfull[128 + d] + v.y * wfull[128 + d + 1]
                 + v.z * wfull[128 + d + 2] + v.w * wfull[128 + d + 3];
            half4 hv;
            hv[0] = (_Float16)v.x; hv[1] = (_Float16)v.y;
            hv[2] = (_Float16)v.z; hv[3] = (_Float16)v.w;
            *(half4*)&qrow[q * QSTR + d] = hv;
            qT2[(d + 0) * QSTR + p] = hv[0];
            qT2[(d + 1) * QSTR + p] = hv[1];
            qT2[(d + 2) * QSTR + p] = hv[2];
            qT2[(d + 3) * QSTR + p] = hv[3];
        }
        acc += __shfl_xor(acc, 1);
        acc += __shfl_xor(acc, 2);
        if (h == 0) qts[q] = acc + (1.0f - mask[b * Qn + q]) * (NEGINF * L2E);
    }
    __syncthreads();

    const int wave = t >> 6, lane = t & 63, g = lane >> 4, l15 = lane & 15;
    const int cw = wave * 16;
    const int cl = cw + l15;   // this lane's ctx row within the 128-tile

    // ---- phase 2: mm1  S'^T[q][c] (log2-scaled fp16) with fused c_term
    f32x4 acc1[8] = {};
    float cterm = 0.f;
#pragma unroll
    for (int kk = 0; kk < 4; ++kk) {
        const int dbase = kk * 32 + g * 8;
        const float* pc = ctxB + (size_t)(c0 + cl) * Dn + dbase;
        f32x4 v0 = *(const f32x4*)pc, v1 = *(const f32x4*)(pc + 4);
        f32x4 s0 = *(const f32x4*)&wfull[256 + dbase], s1 = *(const f32x4*)&wfull[256 + dbase + 4];
        f32x4 c0w = *(const f32x4*)&wfull[dbase], c1w = *(const f32x4*)&wfull[dbase + 4];
        cterm += v0.x * c0w.x + v0.y * c0w.y + v0.z * c0w.z + v0.w * c0w.w
               + v1.x * c1w.x + v1.y * c1w.y + v1.z * c1w.z + v1.w * c1w.w;
        half8 ah;
        ah[0] = (_Float16)(v0.x * s0.x); ah[1] = (_Float16)(v0.y * s0.y);
        ah[2] = (_Float16)(v0.z * s0.z); ah[3] = (_Float16)(v0.w * s0.w);
        ah[4] = (_Float16)(v1.x * s1.x); ah[5] = (_Float16)(v1.y * s1.y);
        ah[6] = (_Float16)(v1.z * s1.z); ah[7] = (_Float16)(v1.w * s1.w);
#pragma unroll
        for (int mt = 0; mt < 8; ++mt) {
            half8 qf = *(const half8*)&qrow[(mt * 16 + l15) * QSTR + dbase];
            acc1[mt] = __builtin_amdgcn_mfma_f32_16x16x32_f16(qf, ah, acc1[mt], 0, 0, 0);
        }
    }
    cterm += __shfl_xor(cterm, 16);
    cterm += __shfl_xor(cterm, 32);   // all lanes: c_term for row cl (log2-scaled)

    // ---- phase 3: +q_term(+mask); softmax (base-2) over q per column
#pragma unroll
    for (int mt = 0; mt < 8; ++mt)
#pragma unroll
        for (int r = 0; r < 4; ++r) acc1[mt][r] += qts[mt * 16 + g * 4 + r];

    float mx = -3.4e38f;
#pragma unroll
    for (int mt = 0; mt < 8; ++mt)
#pragma unroll
        for (int r = 0; r < 4; ++r) mx = fmaxf(mx, acc1[mt][r]);
    mx = fmaxf(mx, __shfl_xor(mx, 16));
    mx = fmaxf(mx, __shfl_xor(mx, 32));
    float sum = 0.f;
#pragma unroll
    for (int mt = 0; mt < 8; ++mt)
#pragma unroll
        for (int r = 0; r < 4; ++r) {
            float pv = exp2fast(acc1[mt][r] - mx);
            acc1[mt][r] = pv;
            sum += pv;
        }
    sum += __shfl_xor(sum, 16);
    sum += __shfl_xor(sum, 32);
    if (g == 0) mloc[cl] = mx + cterm;

    // pack P^T into A-frags (bijection k = 4g+(j&3)+16(j>>2)); inv colsums
    half8 pa[4];
#pragma unroll
    for (int kk2 = 0; kk2 < 4; ++kk2)
#pragma unroll
        for (int j = 0; j < 8; ++j)
            pa[kk2][j] = (_Float16)acc1[2 * kk2 + (j >> 2)][j & 3];

    float inv[4];
#pragma unroll
    for (int r = 0; r < 4; ++r) inv[r] = 1.0f / __shfl(sum, g * 4 + r);

    // ---- mm2: c2q[c][d] = sum_q P[c][q] query[q][d]
    f32x4 acc2[8] = {};
#pragma unroll
    for (int kk2 = 0; kk2 < 4; ++kk2)
#pragma unroll
        for (int ntD = 0; ntD < 8; ++ntD) {
            half8 qb = *(const half8*)&qT2[(ntD * 16 + l15) * QSTR + kk2 * 32 + 8 * g];
            acc2[ntD] = __builtin_amdgcn_mfma_f32_16x16x32_f16(pa[kk2], qb, acc2[ntD], 0, 0, 0);
        }
    __syncthreads();   // qrow/qT2 reads done; mloc complete

    // ---- phase 4a (early): Mloc, wv, Sloc from mloc
    float vm = mloc[t & 127];
    float m = vm;
#pragma unroll
    for (int off = 1; off < 64; off <<= 1) m = fmaxf(m, __shfl_xor(m, off));
    if (lane == 0) red[wave] = m;
    __syncthreads();
    float Mloc = red[0];
#pragma unroll
    for (int i = 1; i < 8; ++i) Mloc = fmaxf(Mloc, red[i]);
    float e = exp2fast(vm - Mloc);
    if (t < 128) wv[t] = e;
    float s = e;
#pragma unroll
    for (int off = 1; off < 64; off <<= 1) s += __shfl_xor(s, off);
    if (lane == 0) red[8 + wave] = s;
    __syncthreads();
    float Sloc = red[8] + red[9];   // waves 0,1 cover t=0..127

    // ---- phase 5: stage c2q into LDS (overlays qrow/qT2; mloc consumed)
#pragma unroll
    for (int r = 0; r < 4; ++r) {
        int c = cw + g * 4 + r;
        float is = inv[r];
#pragma unroll
        for (int ntD = 0; ntD < 8; ++ntD)
            cq[c * CSTR + ntD * 16 + l15] = acc2[ntD][r] * is;
    }
    __syncthreads();

    // ---- phase 6 (fused with 4b): store cols 0,1,2 AND accumulate q2c partial
    const int grp = t >> 5, d4 = (t & 31) * 4;
    f32x4 a = {};
#pragma unroll
    for (int step = 0; step < 8; ++step) {
        int c = grp + step * 16;
        f32x4 q = *(const f32x4*)&cq[c * CSTR + d4];
        f32x4 cv = *(const f32x4*)(ctxB + (size_t)(c0 + c) * Dn + d4);
        float w = wv[c];
        a.x += w * cv.x; a.y += w * cv.y; a.z += w * cv.z; a.w += w * cv.w;
        float* orow = out + ((size_t)(b * Cn + c0 + c)) * 512;
        *(f32x4*)(orow + d4) = cv;
        *(f32x4*)(orow + 128 + d4) = q;
        f32x4 pr;
        pr.x = cv.x * q.x; pr.y = cv.y * q.y; pr.z = cv.z * q.z; pr.w = cv.w * q.w;
        *(f32x4*)(orow + 256 + d4) = pr;
    }
    __syncthreads();   // cq reads done -> partf may overlay

    // ---- tiny tail: reduce 16 partials -> ws
    *(f32x4*)&partf[grp * 128 + d4] = a;
    __syncthreads();
    if (t < 128) {
        float s2 = 0.f;
#pragma unroll
        for (int g2 = 0; g2 < 16; ++g2) s2 += partf[g2 * 128 + t];
        ws_part[((size_t)(b * 8 + cg)) * 128 + t] = s2;
    }
    if (t == 0) {
        ws_ms[(b * 8 + cg) * 2 + 0] = Mloc;
        ws_ms[(b * 8 + cg) * 2 + 1] = Sloc;
    }
}

// ---- k3: combine chunk-partials -> q2c; write col 3 (ctx*q2c) only
// grid (Bn, 8): flat wgid = b + 64*ct -> xcd = b%8, matching k1's placement
// so this batch's ws_part/ws_ms are L2-local.
__global__ __launch_bounds__(256) void k3_kernel(
    const float* __restrict__ ctx, const float* __restrict__ ws_part,
    const float* __restrict__ ws_ms, float* __restrict__ out)
{
    __shared__ float q2cs[128];
    const int b = blockIdx.x, ct = blockIdx.y, t = threadIdx.x;
    if (t < 128) {
        const float* ms = ws_ms + b * 16;
        float Mg = -3.4e38f;
#pragma unroll
        for (int i = 0; i < 8; ++i) Mg = fmaxf(Mg, ms[2 * i]);
        float num = 0.f, den = 0.f;
#pragma unroll
        for (int i = 0; i < 8; ++i) {
            float e = exp2fast(ms[2 * i] - Mg);
            num += e * ws_part[((size_t)(b * 8 + i)) * 128 + t];
            den += e * ms[2 * i + 1];
        }
        q2cs[t] = num / den;
    }
    __syncthreads();
    const float* cb = ctx + ((size_t)b * Cn + ct * 128) * Dn;
    float* ob = out + ((size_t)(b * Cn) + ct * 128) * 512;
    for (int step = 0; step < 16; ++step) {
        int c = (t >> 5) + step * 8, d4 = (t & 31) * 4;
        f32x4 v = *(const f32x4*)(cb + (size_t)c * Dn + d4);
        f32x4 q = *(const f32x4*)&q2cs[d4];
        f32x4 w;
        w.x = v.x * q.x; w.y = v.y * q.y; w.z = v.z * q.z; w.w = v.w * q.w;
        *(f32x4*)(ob + (size_t)c * 512 + 384 + d4) = w;
    }
}

extern "C" void kernel_launch(void* const* d_in, const int* in_sizes, int n_in,
                              void* d_out, int out_size, void* d_ws, size_t ws_size,
                              hipStream_t stream) {
    const float* ctx  = (const float*)d_in[0];
    const float* qry  = (const float*)d_in[1];
    const float* W    = (const float*)d_in[2];
    const float* mask = (const float*)d_in[3];
    float* out = (float*)d_out;

    float* ws_part = (float*)d_ws;                    // 64*8*128 f32
    float* ws_ms   = ws_part + (size_t)Bn * 8 * 128;  // 64*8*2 f32

    k1_kernel<<<dim3(Bn, 8), 512, 0, stream>>>(ctx, qry, W, mask, out, ws_part, ws_ms);
    k3_kernel<<<dim3(Bn, 8), 256, 0, stream>>>(ctx, ws_part, ws_ms, out);
}